// Round 1
// baseline (1189.852 us; speedup 1.0000x reference)
//
#include <hip/hip_runtime.h>
#include <hip/hip_bf16.h>

#define N_NODES 10000
#define N_EDGES 160000

// ---------------------------------------------------------------------------
// pw (per-edge radial weights) dtype helpers: float normally, bf16 fallback
// if the workspace is too small for E*252 floats.
// ---------------------------------------------------------------------------
template <typename T> __device__ inline T to_pw(float v);
template <> __device__ inline float to_pw<float>(float v) { return v; }
template <> __device__ inline __hip_bfloat16 to_pw<__hip_bfloat16>(float v) { return __float2bfloat16(v); }
__device__ inline float from_pw(float v) { return v; }
__device__ inline float from_pw(__hip_bfloat16 v) { return __bfloat162float(v); }

// ---------------------------------------------------------------------------
// CG tensor computation (device-side port of _cg_complex/_q_matrix/_real_cg)
// 15 (l1,l2,l3) combos, flat-packed at fixed offsets, total 615 floats.
// ---------------------------------------------------------------------------
static __device__ const int CG_COMBOS[15][4] = {
  {0,0,0,0},{0,1,1,1},{0,2,2,10},{1,0,1,35},{1,1,0,44},{1,1,1,53},{1,1,2,80},
  {1,2,1,125},{1,2,2,170},{2,0,2,245},{2,1,1,270},{2,1,2,315},{2,2,0,390},
  {2,2,1,415},{2,2,2,490}
};

__device__ inline double factd(int n){ double f=1.0; for(int i=2;i<=n;i++) f*=(double)i; return f; }

__device__ double cg_complex_dev(int j1,int m1,int j2,int m2,int j3,int m3){
  if (m1+m2 != m3) return 0.0;
  double pref = sqrt((2.0*j3+1.0)*factd(j1+j2-j3)*factd(j1-j2+j3)*factd(-j1+j2+j3)/factd(j1+j2+j3+1));
  pref *= sqrt(factd(j1+m1)*factd(j1-m1)*factd(j2+m2)*factd(j2-m2)*factd(j3+m3)*factd(j3-m3));
  int kmin = 0; if (j2-j3-m1 > kmin) kmin = j2-j3-m1; if (j1-j3+m2 > kmin) kmin = j1-j3+m2;
  int kmax = j1+j2-j3; if (j1-m1 < kmax) kmax = j1-m1; if (j2+m2 < kmax) kmax = j2+m2;
  double s = 0.0;
  for (int k=kmin; k<=kmax; ++k){
    double d = factd(k)*factd(j1+j2-j3-k)*factd(j1-m1-k)*factd(j2+m2-k)*factd(j3-j2+m1+k)*factd(j3-j1-m2+k);
    s += ((k&1) ? -1.0 : 1.0)/d;
  }
  return pref*s;
}

__device__ inline void q_elem(int l, int r, int c, double* re, double* im){
  const double s2 = 0.7071067811865476;
  *re = 0.0; *im = 0.0;
  int mr = r - l, mc = c - l;
  if (mr == 0){ if (mc == 0) *re = 1.0; return; }
  if (mr > 0){
    int m = mr;
    if (mc == m)       *re = (m&1) ? -s2 : s2;
    else if (mc == -m) *re = s2;
  } else {
    int m = -mr;
    if (mc == -m)      *im = s2;          //  i*s2
    else if (mc == m)  *im = (m&1) ? s2 : -s2;  // -i*(-1)^m*s2
  }
}

__global__ __launch_bounds__(128) void cg_init_kernel(float* __restrict__ cgbuf){
  __shared__ double Cr[125], Ci[125];
  __shared__ double Qr[3][25], Qi[3][25];
  __shared__ double Kr[125], Ki[125];
  __shared__ double red[128];
  int t = threadIdx.x, b = blockIdx.x;
  int l1 = CG_COMBOS[b][0], l2 = CG_COMBOS[b][1], l3 = CG_COMBOS[b][2], off = CG_COMBOS[b][3];
  int n1 = 2*l1+1, n2 = 2*l2+1, n3 = 2*l3+1;
  int tot = n1*n2*n3;
  for (int i=t; i<tot; i+=128){ Cr[i]=0.0; Ci[i]=0.0; }
  __syncthreads();
  if (t < n1*n2){
    int m1 = t/n2 - l1, m2 = t%n2 - l2, m3 = m1+m2;
    if (m3 >= -l3 && m3 <= l3)
      Cr[t*n3 + (l3+m3)] = cg_complex_dev(l1,m1,l2,m2,l3,m3);
  }
  int ls[3] = {l1,l2,l3};
  for (int q=0;q<3;q++){
    int n = 2*ls[q]+1;
    if (t < n*n) q_elem(ls[q], t/n, t%n, &Qr[q][t], &Qi[q][t]);
  }
  __syncthreads();
  if (t < tot){
    int i = t/(n2*n3), j = (t/n3)%n2, k = t%n3;
    double sr=0.0, si=0.0;
    for (int a=0;a<n1;a++){
      double q1r = Qr[0][i*n1+a], q1i = -Qi[0][i*n1+a];   // conj
      for (int bb=0;bb<n2;bb++){
        double q2r = Qr[1][j*n2+bb], q2i = -Qi[1][j*n2+bb]; // conj
        double pr = q1r*q2r - q1i*q2i, pi = q1r*q2i + q1i*q2r;
        for (int c=0;c<n3;c++){
          double cr = Cr[(a*n2+bb)*n3+c], ci = Ci[(a*n2+bb)*n3+c];
          if (cr==0.0 && ci==0.0) continue;
          double q3r = Qr[2][k*n3+c], q3i = Qi[2][k*n3+c];
          double tr = pr*q3r - pi*q3i, ti = pr*q3i + pi*q3r;
          sr += tr*cr - ti*ci;
          si += tr*ci + ti*cr;
        }
      }
    }
    Kr[t]=sr; Ki[t]=si;
  }
  __syncthreads();
  double v = (t<tot) ? fabs(Kr[t]) : 0.0;
  red[t]=v; __syncthreads();
  for (int s=64;s>0;s>>=1){ if (t<s && red[t+s]>red[t]) red[t]=red[t+s]; __syncthreads(); }
  double maxRe = red[0]; __syncthreads();
  v = (t<tot) ? fabs(Ki[t]) : 0.0;
  red[t]=v; __syncthreads();
  for (int s=64;s>0;s>>=1){ if (t<s && red[t+s]>red[t]) red[t]=red[t+s]; __syncthreads(); }
  double maxIm = red[0]; __syncthreads();
  bool useIm = (maxIm > maxRe);
  double pick = (t<tot) ? (useIm ? -Ki[t] : Kr[t]) : 0.0;   // (1j*K).real == -K.imag
  red[t] = pick*pick; __syncthreads();
  for (int s=64;s>0;s>>=1){ if (t<s) red[t]+=red[t+s]; __syncthreads(); }
  double scale = sqrt((double)n3) / sqrt(red[0]);
  if (t<tot) cgbuf[off+t] = (float)(pick*scale);
}

// ---------------------------------------------------------------------------
// CSR build: histogram -> exclusive scan -> scatter
// ---------------------------------------------------------------------------
__global__ void hist_kernel(const int* __restrict__ dst, int* __restrict__ deg){
  int e = blockIdx.x*256 + threadIdx.x;
  atomicAdd(&deg[dst[e]], 1);
}

__global__ __launch_bounds__(1024) void scan_kernel(const int* __restrict__ deg,
                                                    int* __restrict__ offs,
                                                    int* __restrict__ cursor){
  __shared__ int lds[1024];
  __shared__ int run_s;
  int tid = threadIdx.x;
  if (tid==0) run_s = 0;
  __syncthreads();
  for (int base=0; base<N_NODES; base+=1024){
    int i = base + tid;
    int vv = (i<N_NODES) ? deg[i] : 0;
    lds[tid]=vv; __syncthreads();
    for (int off=1; off<1024; off<<=1){
      int a = lds[tid];
      int b = (tid>=off) ? lds[tid-off] : 0;
      __syncthreads();
      lds[tid] = a + b;
      __syncthreads();
    }
    int incl = lds[tid];
    int run = run_s;
    if (i < N_NODES){ int ex = run + incl - vv; offs[i]=ex; cursor[i]=ex; }
    __syncthreads();
    if (tid==1023) run_s = run + lds[1023];
    __syncthreads();
  }
  if (tid==0) offs[N_NODES] = run_s;
}

__global__ void scatter_kernel(const int* __restrict__ dst, int* __restrict__ cursor,
                               int* __restrict__ eids){
  int e = blockIdx.x*256 + threadIdx.x;
  int p = atomicAdd(&cursor[dst[e]], 1);
  eids[p] = e;
}

// ---------------------------------------------------------------------------
// Per-edge radial MLP: pw[e, 0:WOUT] = silu(emb @ w1) @ w2
// 64-edge tile per 256-thread block; hidden staged in LDS; w2 coalesced.
// ---------------------------------------------------------------------------
template<int WOUT, typename PwT>
__global__ __launch_bounds__(256) void mlp_kernel(const float* __restrict__ edge_vec,
    const float* __restrict__ w1, const float* __restrict__ w2, PwT* __restrict__ pw){
  __shared__ float emb_s[64*10];
  __shared__ float hid_s[100*64];   // [h][e]
  int t = threadIdx.x;
  int eb = blockIdx.x*64;
  if (t < 64){
    int e = eb + t;
    float vx = edge_vec[3*e], vy = edge_vec[3*e+1], vz = edge_vec[3*e+2];
    float r = sqrtf(vx*vx + vy*vy + vz*vz);
    const float EMBC = 1.14136f * 7.3890560989306495f * 3.1622776601683795f; // 1.14136*e^2*sqrt(10)
    #pragma unroll
    for (int bb=0; bb<10; bb++){
      float c = 5.0f*(float)(bb+1)/11.0f;
      float d = (r - c) * (11.0f/5.0f);
      float t1 = d + 1.0f, t2 = 1.0f - d;
      float u1 = (t1 > 0.0f) ? __expf(-1.0f/t1) : 0.0f;
      float u2 = (t2 > 0.0f) ? __expf(-1.0f/t2) : 0.0f;
      emb_s[t*10+bb] = EMBC*u1*u2;
    }
  }
  __syncthreads();
  {
    int e = t & 63, h0 = t >> 6;
    #pragma unroll
    for (int k=0;k<25;k++){
      int h = h0 + 4*k;
      float s = 0.f;
      #pragma unroll
      for (int bb=0;bb<10;bb++) s += emb_s[e*10+bb]*w1[bb*100+h];
      hid_s[h*64+e] = s/(1.0f+__expf(-s));   // silu
    }
  }
  __syncthreads();
  constexpr int NQ = (WOUT+63)/64;
  int cq = t & 63, eg = t >> 6;
  float acc[NQ][16];
  #pragma unroll
  for (int q=0;q<NQ;q++)
    #pragma unroll
    for (int m=0;m<16;m++) acc[q][m]=0.f;
  for (int h=0; h<100; h++){
    float wv[NQ];
    #pragma unroll
    for (int q=0;q<NQ;q++){ int c = cq + 64*q; wv[q] = (c<WOUT) ? w2[h*WOUT+c] : 0.f; }
    #pragma unroll
    for (int m=0;m<16;m++){
      float hv = hid_s[h*64 + eg + 4*m];
      #pragma unroll
      for (int q=0;q<NQ;q++) acc[q][m] += wv[q]*hv;
    }
  }
  #pragma unroll
  for (int m=0;m<16;m++){
    int e = eb + eg + 4*m;
    #pragma unroll
    for (int q=0;q<NQ;q++){
      int c = cq + 64*q;
      if (c < WOUT) pw[(size_t)e*WOUT + c] = to_pw<PwT>(acc[q][m]);
    }
  }
}

// ---------------------------------------------------------------------------
// Conv segment / path tables.
// SEG fields: {cbase, mul, nk, ni, woff, fbase, fstride, goff}
// PATH fields: {goff, ni, nj, nk, yb, cgoff}   (for G[i,k] = sum_j Y[j]*CG[i,j,k])
// ---------------------------------------------------------------------------
static __device__ const int SEG1[3][8] = {
  {0, 8,1, 1, 0,  0,1, 0},
  {8, 8,3, 1, 8,  0,1, 1},
  {32,8,5, 1, 16, 0,1, 4}
};
static __device__ const int PATH1[3][6] = {
  {0, 1,1,1, 0, 0},
  {1, 1,3,3, 1, 1},
  {4, 1,5,5, 4, 10}
};
static __device__ const int SEG2[15][8] = {
  {0,   32,1, 1, 0,   0, 1, 0},    // (0,0,0)
  {32,  16,1, 3, 112, 32,3, 18},   // (1,1,0)
  {48,  10,1, 5, 222, 80,5, 134},  // (2,2,0)
  {58,  32,3, 1, 32,  0, 1, 1},    // (0,1,1)
  {154, 16,3, 3, 96,  32,3, 9},    // (1,0,1)
  {202, 16,3, 3, 128, 32,3, 21},   // (1,1,1)
  {250, 16,3, 3, 160, 32,3, 45},   // (1,2,1)
  {298, 10,3, 5, 202, 80,5, 94},   // (2,1,1)
  {328, 10,3, 5, 232, 80,5, 139},  // (2,2,1)
  {358, 32,5, 1, 64,  0, 1, 4},    // (0,2,2)
  {518, 16,5, 3, 144, 32,3, 30},   // (1,1,2)
  {598, 16,5, 3, 176, 32,3, 54},   // (1,2,2)
  {678, 10,5, 5, 192, 80,5, 69},   // (2,0,2)
  {728, 10,5, 5, 212, 80,5, 109},  // (2,1,2)
  {778, 10,5, 5, 242, 80,5, 154}   // (2,2,2)
};
static __device__ const int PATH2[15][6] = {
  {0,   1,1,1, 0, 0},
  {1,   1,3,3, 1, 1},
  {4,   1,5,5, 4, 10},
  {9,   3,1,3, 0, 35},
  {18,  3,3,1, 1, 44},
  {21,  3,3,3, 1, 53},
  {30,  3,3,5, 1, 80},
  {45,  3,5,3, 4, 125},
  {54,  3,5,5, 4, 170},
  {69,  5,1,5, 0, 245},
  {94,  5,3,3, 1, 270},
  {109, 5,3,5, 1, 315},
  {134, 5,5,1, 4, 390},
  {139, 5,5,3, 4, 415},
  {154, 5,5,5, 4, 490}
};
static __device__ const int SEG3[3][8] = {
  {0, 32,1, 1, 0,  0, 1, 0},
  {32,16,1, 3, 32, 32,3, 1},
  {48,10,1, 5, 48, 80,5, 4}
};
static __device__ const int PATH3[3][6] = {
  {0, 1,1,1, 0, 0},
  {1, 3,3,1, 1, 44},
  {4, 5,5,1, 4, 390}
};

template<int LAYER>
__device__ inline void seg_decode(int c, int& wi, int& fi, int& gk, int& nk, int& ni){
  const int (*seg)[8] = (LAYER==1) ? SEG1 : (LAYER==2) ? SEG2 : SEG3;
  const int nseg = (LAYER==2) ? 15 : 3;
  for (int s=0;s<nseg;s++){
    int cb = seg[s][0], cnt = seg[s][1]*seg[s][2];
    if (c >= cb && c < cb+cnt){
      int loc = c - cb, nkk = seg[s][2];
      int u = loc/nkk, k = loc - u*nkk;
      wi = seg[s][4] + u;
      fi = seg[s][5] + u*seg[s][6];
      gk = seg[s][7] + k;
      nk = nkk; ni = seg[s][3];
      return;
    }
  }
}

template<int LAYER>
__device__ inline void path_decode(int g, int& cgb, int& stride, int& nj, int& yb){
  const int (*pt)[6] = (LAYER==1) ? PATH1 : (LAYER==2) ? PATH2 : PATH3;
  const int np = (LAYER==2) ? 15 : 3;
  for (int s=0;s<np;s++){
    int gb = pt[s][0], cnt = pt[s][1]*pt[s][3];
    if (g >= gb && g < gb+cnt){
      int loc = g - gb, nkk = pt[s][3];
      int i = loc/nkk, k = loc - i*nkk;
      nj = pt[s][2]; yb = pt[s][4];
      cgb = pt[s][5] + i*pt[s][2]*nkk + k;  // cgoff + (i*nj + j)*nk + k at j=0
      stride = nkk;
      return;
    }
  }
}

// ---------------------------------------------------------------------------
// Gather conv: one wave per node. Accumulates messages in registers, then
// fused epilogue: x0.25, lin, self-connection, gate -> node features (or out).
// ---------------------------------------------------------------------------
template<int LAYER, typename PwT>
__global__ __launch_bounds__(64) void conv_kernel(
    const int* __restrict__ offs, const int* __restrict__ eids,
    const int* __restrict__ edge_src, const float* __restrict__ edge_vec,
    const float* __restrict__ cgbuf, const PwT* __restrict__ pw,
    const float* __restrict__ fin,
    const float* __restrict__ linA, const float* __restrict__ linB, const float* __restrict__ linC,
    const float* __restrict__ scA, const float* __restrict__ scB, const float* __restrict__ scC,
    const float* __restrict__ gw,
    float* __restrict__ outp)
{
  constexpr int C    = (LAYER==1) ? 72  : (LAYER==2) ? 828 : 58;
  constexpr int T    = (C+63)/64;
  constexpr int W    = (LAYER==1) ? 24  : (LAYER==2) ? 252 : 58;
  constexpr int FIN  = (LAYER==1) ? 8   : 130;
  constexpr int GTOT = (LAYER==2) ? 179 : 9;
  constexpr int TG   = (GTOT+63)/64;

  __shared__ float cg_s[615];
  __shared__ float Y_s[9];
  __shared__ float G_s[GTOT];
  __shared__ float pw_s[W];
  __shared__ float f_s[FIN];
  __shared__ float row_s[C];
  __shared__ float s0_s[32];
  __shared__ float g_s[26];

  int lane = threadIdx.x;
  int n = blockIdx.x;
  for (int i=lane;i<615;i+=64) cg_s[i] = cgbuf[i];

  // per-lane message-channel descriptors (fixed for the whole kernel)
  int d_w[T], d_f[T], d_g[T], d_nk[T], d_ni[T];
  #pragma unroll
  for (int tt=0;tt<T;tt++){
    int c = lane + 64*tt;
    d_ni[tt] = 0;
    if (c < C) seg_decode<LAYER>(c, d_w[tt], d_f[tt], d_g[tt], d_nk[tt], d_ni[tt]);
  }
  // per-lane G descriptors
  int gd_b[TG], gd_st[TG], gd_nj[TG], gd_yb[TG];
  #pragma unroll
  for (int tg=0;tg<TG;tg++){
    int g = lane + 64*tg;
    gd_nj[tg] = 0;
    if (g < GTOT) path_decode<LAYER>(g, gd_b[tg], gd_st[tg], gd_nj[tg], gd_yb[tg]);
  }

  float acc[T];
  #pragma unroll
  for (int tt=0;tt<T;tt++) acc[tt]=0.f;

  int beg = offs[n], end = offs[n+1];
  __syncthreads();

  for (int idx=beg; idx<end; ++idx){
    int e = eids[idx];
    int src = edge_src[e];
    if (lane==0){
      float vx = edge_vec[3*e], vy = edge_vec[3*e+1], vz = edge_vec[3*e+2];
      float rinv = rsqrtf(vx*vx + vy*vy + vz*vz);
      float x = vx*rinv, y = vy*rinv, z = vz*rinv;
      Y_s[0] = 1.f;
      Y_s[1] = 1.7320508075688772f*y;
      Y_s[2] = 1.7320508075688772f*z;
      Y_s[3] = 1.7320508075688772f*x;
      Y_s[4] = 3.872983346207417f*x*y;
      Y_s[5] = 3.872983346207417f*y*z;
      Y_s[6] = 0.5f*2.23606797749979f*(3.f*z*z - 1.f);
      Y_s[7] = 3.872983346207417f*x*z;
      Y_s[8] = 0.5f*3.872983346207417f*(x*x - y*y);
    }
    for (int i=lane;i<W;i+=64)   pw_s[i] = from_pw(pw[(size_t)e*W + i]);
    for (int i=lane;i<FIN;i+=64) f_s[i]  = fin[(size_t)src*FIN + i];
    __syncthreads();
    // G[i,k] = sum_j Y[j]*CG[i,j,k]
    #pragma unroll
    for (int tg=0;tg<TG;tg++){
      if (gd_nj[tg] > 0){
        float s = 0.f;
        for (int j=0;j<gd_nj[tg];j++) s += Y_s[gd_yb[tg]+j]*cg_s[gd_b[tg] + j*gd_st[tg]];
        G_s[lane + 64*tg] = s;
      }
    }
    __syncthreads();
    // messages: acc[c] += pw[woff+u] * sum_i f[u,i] * G[i,k]
    #pragma unroll
    for (int tt=0;tt<T;tt++){
      if (d_ni[tt] > 0){
        float s = 0.f;
        for (int i=0;i<d_ni[tt];i++) s += f_s[d_f[tt]+i]*G_s[d_g[tt] + i*d_nk[tt]];
        acc[tt] += pw_s[d_w[tt]]*s;
      }
    }
    __syncthreads();
  }

  // ---- epilogue ----
  #pragma unroll
  for (int tt=0;tt<T;tt++){ int c = lane + 64*tt; if (c < C) row_s[c] = acc[tt]*0.25f; }
  if constexpr (LAYER==1){
    if (lane < 8) f_s[lane] = fin[n*8 + lane];
  } else {
    for (int i=lane;i<130;i+=64) f_s[i] = fin[(size_t)n*130 + i];
  }
  __syncthreads();

  if constexpr (LAYER==3){
    float v = 0.f;
    if (lane < 58) v += row_s[lane]*linA[lane];
    if (lane < 32) v += f_s[lane]*scA[lane];
    for (int d=32; d>0; d>>=1) v += __shfl_down(v, d, 64);
    if (lane==0) outp[n] = v;
  } else {
    constexpr int NU0  = (LAYER==1) ? 8 : 58;   // lin rows for l=0
    constexpr int NSC0 = (LAYER==1) ? 8 : 32;   // sc rows for l=0
    if (lane < 32){
      float s = 0.f;
      for (int u=0;u<NU0;u++)  s += row_s[u]*linA[u*32+lane];
      for (int u=0;u<NSC0;u++) s += f_s[u]*scA[u*32+lane];
      s0_s[lane] = s;
    }
    __syncthreads();
    if (lane < 26){
      float s = 0.f;
      for (int v2=0;v2<32;v2++) s += s0_s[v2]*gw[v2*26+lane];
      g_s[lane] = 1.f/(1.f + __expf(-s));
    }
    __syncthreads();
    for (int c=lane;c<130;c+=64){
      float val;
      if (c < 32){
        float s = s0_s[c];
        val = s/(1.f + __expf(-s));           // silu
      } else if (c < 80){
        int u = (c-32)/3, k = (c-32)%3;
        float s = 0.f;
        if constexpr (LAYER==1){
          for (int up=0;up<8;up++) s += row_s[8 + up*3 + k]*linB[up*16+u];
        } else {
          for (int U=0;U<100;U++)  s += row_s[58 + U*3 + k]*linB[U*16+u];
          for (int up=0;up<16;up++) s += f_s[32 + up*3 + k]*scB[up*16+u];
        }
        val = s*g_s[u];
      } else {
        int u = (c-80)/5, k = (c-80)%5;
        float s = 0.f;
        if constexpr (LAYER==1){
          for (int up=0;up<8;up++) s += row_s[32 + up*5 + k]*linC[up*10+u];
        } else {
          for (int U=0;U<94;U++)   s += row_s[358 + U*5 + k]*linC[U*10+u];
          for (int up=0;up<10;up++) s += f_s[80 + up*5 + k]*scC[up*10+u];
        }
        val = s*g_s[16+u];
      }
      outp[(size_t)n*130 + c] = val;
    }
  }
}

// ---------------------------------------------------------------------------
template<typename PwT>
static void run_layers(const float* x, const float* edge_vec,
    const float* fc1_w1, const float* fc1_w2,
    const float* lin1_l0, const float* lin1_l1, const float* lin1_l2,
    const float* sc1_l0, const float* gate1_w,
    const float* fc2_w1, const float* fc2_w2,
    const float* lin2_l0, const float* lin2_l1, const float* lin2_l2,
    const float* sc2_l0, const float* sc2_l1, const float* sc2_l2, const float* gate2_w,
    const float* fc3_w1, const float* fc3_w2, const float* lin3_l0, const float* sc3_l0,
    const int* offs, const int* eids, const int* edge_src,
    const float* cgbuf, PwT* pw, float* hfeats, float* h2feats, float* out,
    hipStream_t stream)
{
  mlp_kernel<24,PwT><<<N_EDGES/64, 256, 0, stream>>>(edge_vec, fc1_w1, fc1_w2, pw);
  conv_kernel<1,PwT><<<N_NODES, 64, 0, stream>>>(offs, eids, edge_src, edge_vec, cgbuf, pw,
      x, lin1_l0, lin1_l1, lin1_l2, sc1_l0, nullptr, nullptr, gate1_w, hfeats);
  mlp_kernel<252,PwT><<<N_EDGES/64, 256, 0, stream>>>(edge_vec, fc2_w1, fc2_w2, pw);
  conv_kernel<2,PwT><<<N_NODES, 64, 0, stream>>>(offs, eids, edge_src, edge_vec, cgbuf, pw,
      hfeats, lin2_l0, lin2_l1, lin2_l2, sc2_l0, sc2_l1, sc2_l2, gate2_w, h2feats);
  mlp_kernel<58,PwT><<<N_EDGES/64, 256, 0, stream>>>(edge_vec, fc3_w1, fc3_w2, pw);
  conv_kernel<3,PwT><<<N_NODES, 64, 0, stream>>>(offs, eids, edge_src, edge_vec, cgbuf, pw,
      h2feats, lin3_l0, nullptr, nullptr, sc3_l0, nullptr, nullptr, nullptr, out);
}

extern "C" void kernel_launch(void* const* d_in, const int* in_sizes, int n_in,
                              void* d_out, int out_size, void* d_ws, size_t ws_size,
                              hipStream_t stream){
  (void)in_sizes; (void)n_in; (void)out_size;
  const float* x        = (const float*)d_in[0];
  const float* edge_vec = (const float*)d_in[1];
  const float* fc1_w1   = (const float*)d_in[2];
  const float* fc1_w2   = (const float*)d_in[3];
  const float* lin1_l0  = (const float*)d_in[4];
  const float* lin1_l1  = (const float*)d_in[5];
  const float* lin1_l2  = (const float*)d_in[6];
  const float* sc1_l0   = (const float*)d_in[7];
  const float* gate1_w  = (const float*)d_in[8];
  const float* fc2_w1   = (const float*)d_in[9];
  const float* fc2_w2   = (const float*)d_in[10];
  const float* lin2_l0  = (const float*)d_in[11];
  const float* lin2_l1  = (const float*)d_in[12];
  const float* lin2_l2  = (const float*)d_in[13];
  const float* sc2_l0   = (const float*)d_in[14];
  const float* sc2_l1   = (const float*)d_in[15];
  const float* sc2_l2   = (const float*)d_in[16];
  const float* gate2_w  = (const float*)d_in[17];
  const float* fc3_w1   = (const float*)d_in[18];
  const float* fc3_w2   = (const float*)d_in[19];
  const float* lin3_l0  = (const float*)d_in[20];
  const float* sc3_l0   = (const float*)d_in[21];
  const int* edge_src   = (const int*)d_in[22];
  const int* edge_dst   = (const int*)d_in[23];
  float* out = (float*)d_out;

  char* base = (char*)d_ws;
  size_t off = 0;
  auto carve = [&](size_t bytes)->char*{
    char* p = base + off;
    off = (off + bytes + 255) & ~(size_t)255;
    return p;
  };
  int*   deg     = (int*)  carve((size_t)N_NODES*4);
  int*   offs    = (int*)  carve((size_t)(N_NODES+1)*4);
  int*   cursor  = (int*)  carve((size_t)N_NODES*4);
  int*   eids    = (int*)  carve((size_t)N_EDGES*4);
  float* cgbuf   = (float*)carve(615*4);
  float* hfeats  = (float*)carve((size_t)N_NODES*130*4);
  float* h2feats = (float*)carve((size_t)N_NODES*130*4);
  size_t fixed = off;
  void* pwbuf = (void*)(base + fixed);
  size_t need_f32 = fixed + (size_t)N_EDGES*252*4;

  hipMemsetAsync(deg, 0, (size_t)N_NODES*4, stream);
  hist_kernel<<<N_EDGES/256, 256, 0, stream>>>(edge_dst, deg);
  scan_kernel<<<1, 1024, 0, stream>>>(deg, offs, cursor);
  scatter_kernel<<<N_EDGES/256, 256, 0, stream>>>(edge_dst, cursor, eids);
  cg_init_kernel<<<15, 128, 0, stream>>>(cgbuf);

  if (ws_size >= need_f32){
    run_layers<float>(x, edge_vec, fc1_w1, fc1_w2, lin1_l0, lin1_l1, lin1_l2, sc1_l0, gate1_w,
        fc2_w1, fc2_w2, lin2_l0, lin2_l1, lin2_l2, sc2_l0, sc2_l1, sc2_l2, gate2_w,
        fc3_w1, fc3_w2, lin3_l0, sc3_l0,
        offs, eids, edge_src, cgbuf, (float*)pwbuf, hfeats, h2feats, out, stream);
  } else {
    run_layers<__hip_bfloat16>(x, edge_vec, fc1_w1, fc1_w2, lin1_l0, lin1_l1, lin1_l2, sc1_l0, gate1_w,
        fc2_w1, fc2_w2, lin2_l0, lin2_l1, lin2_l2, sc2_l0, sc2_l1, sc2_l2, gate2_w,
        fc3_w1, fc3_w2, lin3_l0, sc3_l0,
        offs, eids, edge_src, cgbuf, (__hip_bfloat16*)pwbuf, hfeats, h2feats, out, stream);
  }
}

// Round 2
// 652.816 us; speedup vs baseline: 1.8226x; 1.8226x over previous
//
#include <hip/hip_runtime.h>
#include <hip/hip_bf16.h>

#define N_NODES 10000
#define N_EDGES 160000

// ===========================================================================
// CG tensor computation (device-side, validated round 1)
// ===========================================================================
static __device__ const int CG_COMBOS[15][4] = {
  {0,0,0,0},{0,1,1,1},{0,2,2,10},{1,0,1,35},{1,1,0,44},{1,1,1,53},{1,1,2,80},
  {1,2,1,125},{1,2,2,170},{2,0,2,245},{2,1,1,270},{2,1,2,315},{2,2,0,390},
  {2,2,1,415},{2,2,2,490}
};

__device__ inline double factd(int n){ double f=1.0; for(int i=2;i<=n;i++) f*=(double)i; return f; }

__device__ double cg_complex_dev(int j1,int m1,int j2,int m2,int j3,int m3){
  if (m1+m2 != m3) return 0.0;
  double pref = sqrt((2.0*j3+1.0)*factd(j1+j2-j3)*factd(j1-j2+j3)*factd(-j1+j2+j3)/factd(j1+j2+j3+1));
  pref *= sqrt(factd(j1+m1)*factd(j1-m1)*factd(j2+m2)*factd(j2-m2)*factd(j3+m3)*factd(j3-m3));
  int kmin = 0; if (j2-j3-m1 > kmin) kmin = j2-j3-m1; if (j1-j3+m2 > kmin) kmin = j1-j3+m2;
  int kmax = j1+j2-j3; if (j1-m1 < kmax) kmax = j1-m1; if (j2+m2 < kmax) kmax = j2+m2;
  double s = 0.0;
  for (int k=kmin; k<=kmax; ++k){
    double d = factd(k)*factd(j1+j2-j3-k)*factd(j1-m1-k)*factd(j2+m2-k)*factd(j3-j2+m1+k)*factd(j3-j1-m2+k);
    s += ((k&1) ? -1.0 : 1.0)/d;
  }
  return pref*s;
}

__device__ inline void q_elem(int l, int r, int c, double* re, double* im){
  const double s2 = 0.7071067811865476;
  *re = 0.0; *im = 0.0;
  int mr = r - l, mc = c - l;
  if (mr == 0){ if (mc == 0) *re = 1.0; return; }
  if (mr > 0){
    int m = mr;
    if (mc == m)       *re = (m&1) ? -s2 : s2;
    else if (mc == -m) *re = s2;
  } else {
    int m = -mr;
    if (mc == -m)      *im = s2;
    else if (mc == m)  *im = (m&1) ? s2 : -s2;
  }
}

__global__ __launch_bounds__(128) void cg_init_kernel(float* __restrict__ cgbuf){
  __shared__ double Cr[125], Ci[125];
  __shared__ double Qr[3][25], Qi[3][25];
  __shared__ double Kr[125], Ki[125];
  __shared__ double red[128];
  int t = threadIdx.x, b = blockIdx.x;
  int l1 = CG_COMBOS[b][0], l2 = CG_COMBOS[b][1], l3 = CG_COMBOS[b][2], off = CG_COMBOS[b][3];
  int n1 = 2*l1+1, n2 = 2*l2+1, n3 = 2*l3+1;
  int tot = n1*n2*n3;
  for (int i=t; i<tot; i+=128){ Cr[i]=0.0; Ci[i]=0.0; }
  __syncthreads();
  if (t < n1*n2){
    int m1 = t/n2 - l1, m2 = t%n2 - l2, m3 = m1+m2;
    if (m3 >= -l3 && m3 <= l3)
      Cr[t*n3 + (l3+m3)] = cg_complex_dev(l1,m1,l2,m2,l3,m3);
  }
  int ls[3] = {l1,l2,l3};
  for (int q=0;q<3;q++){
    int n = 2*ls[q]+1;
    if (t < n*n) q_elem(ls[q], t/n, t%n, &Qr[q][t], &Qi[q][t]);
  }
  __syncthreads();
  if (t < tot){
    int i = t/(n2*n3), j = (t/n3)%n2, k = t%n3;
    double sr=0.0, si=0.0;
    for (int a=0;a<n1;a++){
      double q1r = Qr[0][i*n1+a], q1i = -Qi[0][i*n1+a];
      for (int bb=0;bb<n2;bb++){
        double q2r = Qr[1][j*n2+bb], q2i = -Qi[1][j*n2+bb];
        double pr = q1r*q2r - q1i*q2i, pi = q1r*q2i + q1i*q2r;
        for (int c=0;c<n3;c++){
          double cr = Cr[(a*n2+bb)*n3+c], ci = Ci[(a*n2+bb)*n3+c];
          if (cr==0.0 && ci==0.0) continue;
          double q3r = Qr[2][k*n3+c], q3i = Qi[2][k*n3+c];
          double tr = pr*q3r - pi*q3i, ti = pr*q3i + pi*q3r;
          sr += tr*cr - ti*ci;
          si += tr*ci + ti*cr;
        }
      }
    }
    Kr[t]=sr; Ki[t]=si;
  }
  __syncthreads();
  double v = (t<tot) ? fabs(Kr[t]) : 0.0;
  red[t]=v; __syncthreads();
  for (int s=64;s>0;s>>=1){ if (t<s && red[t+s]>red[t]) red[t]=red[t+s]; __syncthreads(); }
  double maxRe = red[0]; __syncthreads();
  v = (t<tot) ? fabs(Ki[t]) : 0.0;
  red[t]=v; __syncthreads();
  for (int s=64;s>0;s>>=1){ if (t<s && red[t+s]>red[t]) red[t]=red[t+s]; __syncthreads(); }
  double maxIm = red[0]; __syncthreads();
  bool useIm = (maxIm > maxRe);
  double pick = (t<tot) ? (useIm ? -Ki[t] : Kr[t]) : 0.0;
  red[t] = pick*pick; __syncthreads();
  for (int s=64;s>0;s>>=1){ if (t<s) red[t]+=red[t+s]; __syncthreads(); }
  double scale = sqrt((double)n3) / sqrt(red[0]);
  if (t<tot) cgbuf[off+t] = (float)(pick*scale);
}

// ===========================================================================
// CSR build: histogram -> scan -> scatter (+pos) -> permute src/vec
// ===========================================================================
__global__ void hist_kernel(const int* __restrict__ dst, int* __restrict__ deg){
  int e = blockIdx.x*256 + threadIdx.x;
  atomicAdd(&deg[dst[e]], 1);
}

__global__ __launch_bounds__(1024) void scan_kernel(const int* __restrict__ deg,
                                                    int* __restrict__ offs,
                                                    int* __restrict__ cursor){
  __shared__ int lds[1024];
  __shared__ int run_s;
  int tid = threadIdx.x;
  if (tid==0) run_s = 0;
  __syncthreads();
  for (int base=0; base<N_NODES; base+=1024){
    int i = base + tid;
    int vv = (i<N_NODES) ? deg[i] : 0;
    lds[tid]=vv; __syncthreads();
    for (int off=1; off<1024; off<<=1){
      int a = lds[tid];
      int b = (tid>=off) ? lds[tid-off] : 0;
      __syncthreads();
      lds[tid] = a + b;
      __syncthreads();
    }
    int incl = lds[tid];
    int run = run_s;
    if (i < N_NODES){ int ex = run + incl - vv; offs[i]=ex; cursor[i]=ex; }
    __syncthreads();
    if (tid==1023) run_s = run + lds[1023];
    __syncthreads();
  }
  if (tid==0) offs[N_NODES] = run_s;
}

__global__ void scatter_kernel(const int* __restrict__ dst, int* __restrict__ cursor,
                               int* __restrict__ eids, int* __restrict__ pos){
  int e = blockIdx.x*256 + threadIdx.x;
  int p = atomicAdd(&cursor[dst[e]], 1);
  eids[p] = e;
  pos[e] = p;
}

__global__ void perm_kernel(const int* __restrict__ eids, const int* __restrict__ edge_src,
                            const float* __restrict__ edge_vec,
                            int* __restrict__ src_perm, float* __restrict__ vec_perm){
  int p = blockIdx.x*256 + threadIdx.x;
  int e = eids[p];
  src_perm[p] = edge_src[e];
  vec_perm[3*p]   = edge_vec[3*e];
  vec_perm[3*p+1] = edge_vec[3*e+1];
  vec_perm[3*p+2] = edge_vec[3*e+2];
}

// ===========================================================================
// Per-edge radial MLP, writes pw rows in CSR order (pos permutation).
// hid_s column-swizzled so the main loop reads broadcast ds_read_b128.
// ===========================================================================
template<int WOUT, int WST>
__global__ __launch_bounds__(256) void mlp_kernel(const float* __restrict__ edge_vec,
    const float* __restrict__ w1, const float* __restrict__ w2,
    const int* __restrict__ pos, float* __restrict__ pw){
  __shared__ __align__(16) float emb_s[64*10];
  __shared__ __align__(16) float hid_s[100*64];   // [h][col], col = (e&3)*16 + (e>>2)
  __shared__ int pos_s[64];
  int t = threadIdx.x;
  int eb = blockIdx.x*64;
  if (t < 64){
    int e = eb + t;
    pos_s[t] = pos[e];
    float vx = edge_vec[3*e], vy = edge_vec[3*e+1], vz = edge_vec[3*e+2];
    float r = sqrtf(vx*vx + vy*vy + vz*vz);
    const float EMBC = 1.14136f * 7.3890560989306495f * 3.1622776601683795f;
    #pragma unroll
    for (int bb=0; bb<10; bb++){
      float c = 5.0f*(float)(bb+1)/11.0f;
      float d = (r - c) * (11.0f/5.0f);
      float t1 = d + 1.0f, t2 = 1.0f - d;
      float u1 = (t1 > 0.0f) ? __expf(-1.0f/t1) : 0.0f;
      float u2 = (t2 > 0.0f) ? __expf(-1.0f/t2) : 0.0f;
      emb_s[t*10+bb] = EMBC*u1*u2;
    }
  }
  __syncthreads();
  {
    int e = t & 63, h0 = t >> 6;
    int col = ((e&3)<<4) | (e>>2);
    #pragma unroll
    for (int k=0;k<25;k++){
      int h = h0 + 4*k;
      float s = 0.f;
      #pragma unroll
      for (int bb=0;bb<10;bb++) s += emb_s[e*10+bb]*w1[bb*100+h];
      hid_s[h*64+col] = s/(1.0f+__expf(-s));
    }
  }
  __syncthreads();
  constexpr int NQ = (WOUT+63)/64;
  int cq = t & 63, eg = t >> 6;
  float acc[NQ][16];
  #pragma unroll
  for (int q=0;q<NQ;q++)
    #pragma unroll
    for (int m=0;m<16;m++) acc[q][m]=0.f;
  for (int h=0; h<100; h++){
    float wv[NQ];
    #pragma unroll
    for (int q=0;q<NQ;q++){ int c = cq + 64*q; wv[q] = (c<WOUT) ? w2[h*WOUT+c] : 0.f; }
    const float4* hp = (const float4*)&hid_s[h*64 + (eg<<4)];
    float4 ha = hp[0], hb = hp[1], hc = hp[2], hd = hp[3];
    float hv[16] = {ha.x,ha.y,ha.z,ha.w, hb.x,hb.y,hb.z,hb.w,
                    hc.x,hc.y,hc.z,hc.w, hd.x,hd.y,hd.z,hd.w};
    #pragma unroll
    for (int m=0;m<16;m++){
      #pragma unroll
      for (int q=0;q<NQ;q++) acc[q][m] += wv[q]*hv[m];
    }
  }
  #pragma unroll
  for (int m=0;m<16;m++){
    int row = pos_s[eg + 4*m];
    #pragma unroll
    for (int q=0;q<NQ;q++){
      int c = cq + 64*q;
      if (c < WOUT) pw[(size_t)row*WST + c] = acc[q][m];
    }
  }
}

// ===========================================================================
// Conv: one wave per node, wave-synchronous (no __syncthreads).
// ===========================================================================
#define WAVE_SYNC() asm volatile("s_waitcnt lgkmcnt(0)" ::: "memory")

// Padded G-layout path tables: {base, alloc, S, ni, nk, nj, yb, cgoff}
static __device__ const short GP1[3][8] = {
  {0,4,1,1,1,1,0,0},{4,4,4,1,3,3,1,1},{8,8,8,1,5,5,4,10}
};
static __device__ const short GP3[3][8] = {
  {0,8,1,1,1,1,0,0},{8,8,1,3,1,3,1,44},{16,8,1,5,1,5,4,390}
};
static __device__ const short GP2[15][8] = {
  {0,4,1,1,1,1,0,0},     // p000
  {4,4,4,1,3,3,1,1},     // p011
  {8,8,8,1,5,5,4,10},    // p022
  {16,12,4,3,3,1,0,35},  // p101
  {28,4,1,3,1,3,1,44},   // p110
  {32,12,4,3,3,3,1,53},  // p111
  {44,24,8,3,5,3,1,80},  // p112
  {68,12,4,3,3,5,4,125}, // p121
  {80,24,8,3,5,5,4,170}, // p122
  {104,40,8,5,5,1,0,245},// p202
  {144,20,4,5,3,3,1,270},// p211
  {164,40,8,5,5,3,1,315},// p212
  {204,8,1,5,1,5,4,390}, // p220
  {212,20,4,5,3,5,4,415},// p221
  {232,40,8,5,5,5,4,490} // p222
};

// Layer-2 msg-round subseg table: [round][sub] = {lo, hi, woff, fcls, gbase}
static __device__ const short L2RS[9][3][5] = {
  {{0,32,  0,0,  0},{0,0,0,0,0},{0,0,0,0,0}},
  {{0,32, 32,0,  4},{0,0,0,0,0},{0,0,0,0,0}},
  {{0,32, 64,0,  8},{0,0,0,0,0},{0,0,0,0,0}},
  {{0,16,112,1, 28},{0,0,0,0,0},{0,0,0,0,0}},
  {{0,16, 96,1, 16},{16,32,128,1,32},{32,48,160,1,68}},
  {{0,16,144,1, 44},{16,32,176,1,80},{0,0,0,0,0}},
  {{0,10,222,2,204},{0,0,0,0,0},{0,0,0,0,0}},
  {{0,10,202,2,144},{10,20,232,2,212},{0,0,0,0,0}},
  {{0,10,192,2,104},{10,20,212,2,164},{20,30,242,2,232}}
};
static __device__ const short L2CB[9][3] = {
  {0,0,0},{58,0,0},{358,0,0},{32,0,0},{154,202,250},{518,598,0},{48,0,0},{298,328,0},{678,728,778}
};

template<int NI,int NK>
__device__ inline void mac_seg(const float* __restrict__ fS, const float* __restrict__ gS,
                               const float* __restrict__ pS, unsigned d, float* a){
  float p = pS[d & 255];
  int fb = (d>>8)&255, gb = (int)(d>>16);
  float f[5];
  if constexpr (NI==1){ f[0]=fS[fb]*p; }
  else if constexpr (NI==3){
    float4 t=*(const float4*)(fS+fb); f[0]=t.x*p; f[1]=t.y*p; f[2]=t.z*p;
  } else {
    float4 t=*(const float4*)(fS+fb); f[0]=t.x*p;f[1]=t.y*p;f[2]=t.z*p;f[3]=t.w*p; f[4]=fS[fb+4]*p;
  }
  if constexpr (NK==1){
    if constexpr (NI==1){ a[0] += f[0]*gS[gb]; }
    else {
      float4 g=*(const float4*)(gS+gb);
      float s = f[0]*g.x + f[1]*g.y + f[2]*g.z;
      if constexpr (NI==5) s += f[3]*g.w + f[4]*gS[gb+4];
      a[0] += s;
    }
  } else {
    constexpr int ST = (NK==3)?4:8;
    #pragma unroll
    for (int i=0;i<NI;i++){
      float4 g=*(const float4*)(gS+gb+i*ST);
      a[0]+=f[i]*g.x; a[1]+=f[i]*g.y; a[2]+=f[i]*g.z;
      if constexpr (NK==5){ a[3]+=f[i]*g.w; a[4]+=f[i]*gS[gb+i*ST+4]; }
    }
  }
}

__device__ inline void mac_seg_l3(const float* __restrict__ fS, const float* __restrict__ gS,
                                  const float* __restrict__ pS, unsigned d, float* a){
  float p = pS[d & 255];
  int fb = (d>>8)&255, gb = (int)(d>>16);
  float4 g=*(const float4*)(gS+gb); float g4=gS[gb+4];
  float s = fS[fb]*g.x + fS[fb+1]*g.y + fS[fb+2]*g.z + fS[fb+3]*g.w + fS[fb+4]*g4;
  a[0] += p*s;
}

template<int LAYER>
__global__ __launch_bounds__(64,3) void conv_kernel(
    const int* __restrict__ offs,
    const int* __restrict__ src_perm, const float* __restrict__ vec_perm,
    const float* __restrict__ cgbuf, const float* __restrict__ pw,
    const float* __restrict__ fin,
    const float* __restrict__ linA, const float* __restrict__ linB, const float* __restrict__ linC,
    const float* __restrict__ scA, const float* __restrict__ scB, const float* __restrict__ scC,
    const float* __restrict__ gw,
    float* __restrict__ outp)
{
  constexpr int C     = (LAYER==1) ? 72  : (LAYER==2) ? 828 : 58;
  constexpr int WST   = (LAYER==1) ? 24  : (LAYER==2) ? 252 : 60;
  constexpr int PWSZ  = (LAYER==1) ? 24  : (LAYER==2) ? 252 : 60;
  constexpr int PWL4  = (LAYER==1) ? 6   : (LAYER==2) ? 63  : 15;
  constexpr int FLDS  = (LAYER==1) ? 8   : 180;
  constexpr int GTOTP = (LAYER==1) ? 16  : (LAYER==2) ? 272 : 24;
  constexpr int GR    = (LAYER==2) ? 5 : 1;
  constexpr int NP    = (LAYER==2) ? 15 : 3;
  constexpr int NACC  = (LAYER==1) ? 5 : (LAYER==2) ? 27 : 1;

  __shared__ __align__(16) float pw_s[PWSZ];
  __shared__ __align__(16) float f_s[FLDS];
  __shared__ __align__(16) float G_s[GTOTP];
  __shared__ __align__(16) float row_s[C];
  __shared__ __align__(16) float s0_s[32];
  __shared__ __align__(16) float g_s[26];

  const int lane = threadIdx.x;
  const int n = blockIdx.x;

  // ---- per-lane constant descriptors ----
  // f staging remap (fin global idx -> LDS remapped idx)
  int rm[3] = {-1,-1,-1};
  if constexpr (LAYER != 1){
    #pragma unroll
    for (int r=0;r<3;r++){
      int i = lane + 64*r;
      if (i < 32) rm[r] = i;
      else if (i < 80)  rm[r] = 32 + ((i-32)/3)*4 + (i-32)%3;
      else if (i < 130) rm[r] = 96 + ((i-80)/5)*8 + (i-80)%5;
    }
  }

  // message-round descriptors
  unsigned md[9]; int cbs[9]; int l1nk = 0;
  #pragma unroll
  for (int r=0;r<9;r++){ md[r]=0; cbs[r]=0; }
  if constexpr (LAYER==2){
    constexpr int RNKc[9] = {1,3,5,1,3,5,1,3,5};
    #pragma unroll
    for (int r=0;r<9;r++){
      #pragma unroll
      for (int s=0;s<3;s++){
        int lo = L2RS[r][s][0], hi = L2RS[r][s][1];
        if (hi > lo && lane >= lo && lane < hi){
          int u = lane - lo;
          int fc = L2RS[r][s][3];
          int flds = (fc==0) ? u : (fc==1) ? 32+4*u : 96+8*u;
          md[r] = (unsigned)(L2RS[r][s][2]+u) | ((unsigned)flds<<8) | ((unsigned)L2RS[r][s][4]<<16);
          cbs[r] = L2CB[r][s] + u*RNKc[r];
        }
      }
    }
  } else if constexpr (LAYER==1){
    if (lane < 24){
      int grp = lane >> 3, u = lane & 7;
      int gb = (grp==0) ? 0 : (grp==1) ? 4 : 8;
      md[0] = (unsigned)(grp*8+u) | ((unsigned)u<<8) | ((unsigned)gb<<16);
      cbs[0] = (grp==0) ? u : (grp==1) ? 8+3*u : 32+5*u;
      l1nk = (grp==0) ? 1 : (grp==1) ? 3 : 5;
    }
  } else {
    if (lane < 58){
      int grp = (lane<32) ? 0 : (lane<48) ? 1 : 2;
      int u = lane - ((grp==0)?0:(grp==1)?32:48);
      int flds = (grp==0) ? u : (grp==1) ? 32+4*u : 96+8*u;
      int gb = (grp==0) ? 0 : (grp==1) ? 8 : 16;
      md[0] = (unsigned)(((grp==0)?0:(grp==1)?32:48)+u) | ((unsigned)flds<<8) | ((unsigned)gb<<16);
      cbs[0] = (grp==0) ? u : (grp==1) ? 32+u : 48+u;
    }
  }

  // G-stage descriptors: per-round cg coefficients preloaded to registers
  float cgr[GR][5];
  bool gc0[GR], gc1[GR];
  #pragma unroll
  for (int rg=0;rg<GR;rg++){
    #pragma unroll
    for (int j=0;j<5;j++) cgr[rg][j] = 0.f;
    gc0[rg] = true; gc1[rg] = false;
    int g = lane + 64*rg;
    if (g < GTOTP){
      for (int p=0;p<NP;p++){
        const short* P = (LAYER==1) ? GP1[p] : (LAYER==2) ? GP2[p] : GP3[p];
        int base = P[0], alloc = P[1];
        if (g >= base && g < base+alloc){
          int S = P[2], ni = P[3], nk = P[4], nj = P[5], yb = P[6], cgo = P[7];
          int i, k; bool valid;
          if (S == 1){ i = g - base; k = 0; valid = (i < ni); }
          else { i = (g-base)/S; k = (g-base)%S; valid = (k < nk); }
          gc0[rg] = (yb == 0); gc1[rg] = (yb == 1);
          if (valid){
            #pragma unroll
            for (int j=0;j<5;j++)
              if (j < nj) cgr[rg][j] = cgbuf[cgo + (i*nj+j)*nk + k];
          } else {
            gc0[rg] = true;  // cg all zero -> G = 0
          }
        }
      }
    }
  }

  float acc[NACC];
  #pragma unroll
  for (int i=0;i<NACC;i++) acc[i] = 0.f;

  int beg = offs[n], end = offs[n+1];

  for (int idx=beg; idx<end; ++idx){
    int src = src_perm[idx];
    float vx = vec_perm[3*idx], vy = vec_perm[3*idx+1], vz = vec_perm[3*idx+2];

    float4 pwv = {0,0,0,0};
    if (lane < PWL4) pwv = *(const float4*)&pw[(size_t)idx*WST + lane*4];
    float fv[3] = {0,0,0};
    if constexpr (LAYER==1){
      if (lane < 8) fv[0] = fin[(size_t)src*8 + lane];
    } else {
      #pragma unroll
      for (int r=0;r<3;r++){
        int i = lane + 64*r;
        if (i < 130) fv[r] = fin[(size_t)src*130 + i];
      }
    }

    // Y in registers (all lanes)
    float rinv = rsqrtf(vx*vx + vy*vy + vz*vz);
    float X = vx*rinv, Yv = vy*rinv, Z = vz*rinv;
    const float c3 = 1.7320508075688772f, c15 = 3.872983346207417f;
    float y1 = c3*Yv, y2 = c3*Z, y3 = c3*X;
    float y4 = c15*X*Yv, y5 = c15*Yv*Z, y6 = 1.118033988749895f*(3.f*Z*Z-1.f);
    float y7 = c15*X*Z, y8 = 0.5f*c15*(X*X - Yv*Yv);

    WAVE_SYNC();   // WAR: previous iteration's LDS reads complete

    if (lane < PWL4) *(float4*)&pw_s[lane*4] = pwv;
    if constexpr (LAYER==1){
      if (lane < 8) f_s[lane] = fv[0];
    } else {
      #pragma unroll
      for (int r=0;r<3;r++) if (rm[r] >= 0) f_s[rm[r]] = fv[r];
    }

    // G stage: pure VALU from register cg, then one ds_write per round
    #pragma unroll
    for (int rg=0;rg<GR;rg++){
      int g = lane + 64*rg;
      if (g < GTOTP){
        float ya = gc1[rg] ? y1 : y4;
        float yb2 = gc1[rg] ? y2 : y5;
        float yc = gc1[rg] ? y3 : y6;
        float t = cgr[rg][0]*ya + cgr[rg][1]*yb2 + cgr[rg][2]*yc + cgr[rg][3]*y7 + cgr[rg][4]*y8;
        G_s[g] = gc0[rg] ? cgr[rg][0] : t;
      }
    }

    WAVE_SYNC();   // RAW: staged data visible

    if constexpr (LAYER==2){
      if (lane<32) mac_seg<1,1>(f_s,G_s,pw_s,md[0],&acc[0]);
      if (lane<32) mac_seg<1,3>(f_s,G_s,pw_s,md[1],&acc[1]);
      if (lane<32) mac_seg<1,5>(f_s,G_s,pw_s,md[2],&acc[4]);
      if (lane<16) mac_seg<3,1>(f_s,G_s,pw_s,md[3],&acc[9]);
      if (lane<48) mac_seg<3,3>(f_s,G_s,pw_s,md[4],&acc[10]);
      if (lane<32) mac_seg<3,5>(f_s,G_s,pw_s,md[5],&acc[13]);
      if (lane<10) mac_seg<5,1>(f_s,G_s,pw_s,md[6],&acc[18]);
      if (lane<20) mac_seg<5,3>(f_s,G_s,pw_s,md[7],&acc[19]);
      if (lane<30) mac_seg<5,5>(f_s,G_s,pw_s,md[8],&acc[22]);
    } else if constexpr (LAYER==1){
      if (lane<24) mac_seg<1,5>(f_s,G_s,pw_s,md[0],&acc[0]);
    } else {
      if (lane<58) mac_seg_l3(f_s,G_s,pw_s,md[0],&acc[0]);
    }
  }

  // ---- epilogue ----
  WAVE_SYNC();
  constexpr float inv = 0.25f;
  if constexpr (LAYER==2){
    constexpr int RNKc[9] = {1,3,5,1,3,5,1,3,5};
    constexpr int AB[9]   = {0,1,4,9,10,13,18,19,22};
    constexpr int CNTc[9] = {32,32,32,16,48,32,10,20,30};
    #pragma unroll
    for (int r=0;r<9;r++){
      if (lane < CNTc[r]){
        #pragma unroll
        for (int k=0;k<RNKc[r];k++) row_s[cbs[r]+k] = acc[AB[r]+k]*inv;
      }
    }
  } else if constexpr (LAYER==1){
    if (lane < 24){
      #pragma unroll
      for (int k=0;k<5;k++) if (k < l1nk) row_s[cbs[0]+k] = acc[k]*inv;
    }
  } else {
    if (lane < 58) row_s[cbs[0]] = acc[0]*inv;
  }

  // restage this node's own features for self-connection
  if constexpr (LAYER==1){
    if (lane < 8) f_s[lane] = fin[(size_t)n*8 + lane];
  } else {
    #pragma unroll
    for (int r=0;r<3;r++){
      int i = lane + 64*r;
      if (i < 130 && rm[r] >= 0) f_s[rm[r]] = fin[(size_t)n*130 + i];
    }
  }
  WAVE_SYNC();

  if constexpr (LAYER==3){
    float v = 0.f;
    if (lane < 58) v += row_s[lane]*linA[lane];
    if (lane < 32) v += f_s[lane]*scA[lane];
    #pragma unroll
    for (int d=32; d>0; d>>=1) v += __shfl_down(v, d, 64);
    if (lane==0) outp[n] = v;
  } else {
    constexpr int NU0  = (LAYER==1) ? 8 : 58;
    constexpr int NSC0 = (LAYER==1) ? 8 : 32;
    if (lane < 32){
      float s = 0.f;
      for (int u=0;u<NU0;u++)  s += row_s[u]*linA[u*32+lane];
      for (int u=0;u<NSC0;u++) s += f_s[u]*scA[u*32+lane];
      s0_s[lane] = s;
    }
    WAVE_SYNC();
    if (lane < 26){
      float s = 0.f;
      for (int v2=0;v2<32;v2++) s += s0_s[v2]*gw[v2*26+lane];
      g_s[lane] = 1.f/(1.f + __expf(-s));
    }
    WAVE_SYNC();
    for (int c=lane;c<130;c+=64){
      float val;
      if (c < 32){
        float s = s0_s[c];
        val = s/(1.f + __expf(-s));
      } else if (c < 80){
        int u = (c-32)/3, k = (c-32)%3;
        float s = 0.f;
        if constexpr (LAYER==1){
          for (int up=0;up<8;up++) s += row_s[8 + up*3 + k]*linB[up*16+u];
        } else {
          for (int U=0;U<100;U++)  s += row_s[58 + U*3 + k]*linB[U*16+u];
          for (int up=0;up<16;up++) s += f_s[32 + up*4 + k]*scB[up*16+u];
        }
        val = s*g_s[u];
      } else {
        int u = (c-80)/5, k = (c-80)%5;
        float s = 0.f;
        if constexpr (LAYER==1){
          for (int up=0;up<8;up++) s += row_s[32 + up*5 + k]*linC[up*10+u];
        } else {
          for (int U=0;U<94;U++)   s += row_s[358 + U*5 + k]*linC[U*10+u];
          for (int up=0;up<10;up++) s += f_s[96 + up*8 + k]*scC[up*10+u];
        }
        val = s*g_s[16+u];
      }
      outp[(size_t)n*130 + c] = val;
    }
  }
}

// ===========================================================================
extern "C" void kernel_launch(void* const* d_in, const int* in_sizes, int n_in,
                              void* d_out, int out_size, void* d_ws, size_t ws_size,
                              hipStream_t stream){
  (void)in_sizes; (void)n_in; (void)out_size; (void)ws_size;
  const float* x        = (const float*)d_in[0];
  const float* edge_vec = (const float*)d_in[1];
  const float* fc1_w1   = (const float*)d_in[2];
  const float* fc1_w2   = (const float*)d_in[3];
  const float* lin1_l0  = (const float*)d_in[4];
  const float* lin1_l1  = (const float*)d_in[5];
  const float* lin1_l2  = (const float*)d_in[6];
  const float* sc1_l0   = (const float*)d_in[7];
  const float* gate1_w  = (const float*)d_in[8];
  const float* fc2_w1   = (const float*)d_in[9];
  const float* fc2_w2   = (const float*)d_in[10];
  const float* lin2_l0  = (const float*)d_in[11];
  const float* lin2_l1  = (const float*)d_in[12];
  const float* lin2_l2  = (const float*)d_in[13];
  const float* sc2_l0   = (const float*)d_in[14];
  const float* sc2_l1   = (const float*)d_in[15];
  const float* sc2_l2   = (const float*)d_in[16];
  const float* gate2_w  = (const float*)d_in[17];
  const float* fc3_w1   = (const float*)d_in[18];
  const float* fc3_w2   = (const float*)d_in[19];
  const float* lin3_l0  = (const float*)d_in[20];
  const float* sc3_l0   = (const float*)d_in[21];
  const int* edge_src   = (const int*)d_in[22];
  const int* edge_dst   = (const int*)d_in[23];
  float* out = (float*)d_out;

  char* base = (char*)d_ws;
  size_t off = 0;
  auto carve = [&](size_t bytes)->char*{
    char* p = base + off;
    off = (off + bytes + 255) & ~(size_t)255;
    return p;
  };
  int*   deg      = (int*)  carve((size_t)N_NODES*4);
  int*   offs     = (int*)  carve((size_t)(N_NODES+1)*4);
  int*   cursor   = (int*)  carve((size_t)N_NODES*4);
  int*   eids     = (int*)  carve((size_t)N_EDGES*4);
  int*   pos      = (int*)  carve((size_t)N_EDGES*4);
  int*   src_perm = (int*)  carve((size_t)N_EDGES*4);
  float* vec_perm = (float*)carve((size_t)N_EDGES*12);
  float* cgbuf    = (float*)carve(615*4);
  float* hfeats   = (float*)carve((size_t)N_NODES*130*4);
  float* h2feats  = (float*)carve((size_t)N_NODES*130*4);
  float* pwbuf    = (float*)carve((size_t)N_EDGES*252*4);

  hipMemsetAsync(deg, 0, (size_t)N_NODES*4, stream);
  hist_kernel<<<N_EDGES/256, 256, 0, stream>>>(edge_dst, deg);
  scan_kernel<<<1, 1024, 0, stream>>>(deg, offs, cursor);
  scatter_kernel<<<N_EDGES/256, 256, 0, stream>>>(edge_dst, cursor, eids, pos);
  perm_kernel<<<N_EDGES/256, 256, 0, stream>>>(eids, edge_src, edge_vec, src_perm, vec_perm);
  cg_init_kernel<<<15, 128, 0, stream>>>(cgbuf);

  mlp_kernel<24,24><<<N_EDGES/64, 256, 0, stream>>>(edge_vec, fc1_w1, fc1_w2, pos, pwbuf);
  conv_kernel<1><<<N_NODES, 64, 0, stream>>>(offs, src_perm, vec_perm, cgbuf, pwbuf,
      x, lin1_l0, lin1_l1, lin1_l2, sc1_l0, nullptr, nullptr, gate1_w, hfeats);
  mlp_kernel<252,252><<<N_EDGES/64, 256, 0, stream>>>(edge_vec, fc2_w1, fc2_w2, pos, pwbuf);
  conv_kernel<2><<<N_NODES, 64, 0, stream>>>(offs, src_perm, vec_perm, cgbuf, pwbuf,
      hfeats, lin2_l0, lin2_l1, lin2_l2, sc2_l0, sc2_l1, sc2_l2, gate2_w, h2feats);
  mlp_kernel<58,60><<<N_EDGES/64, 256, 0, stream>>>(edge_vec, fc3_w1, fc3_w2, pos, pwbuf);
  conv_kernel<3><<<N_NODES, 64, 0, stream>>>(offs, src_perm, vec_perm, cgbuf, pwbuf,
      h2feats, lin3_l0, nullptr, nullptr, sc3_l0, nullptr, nullptr, nullptr, out);
}